// Round 11
// baseline (369.582 us; speedup 1.0000x reference)
//
#include <hip/hip_runtime.h>

typedef __attribute__((ext_vector_type(8))) short bf16x8;
typedef __attribute__((ext_vector_type(4))) float f32x4;
typedef __attribute__((ext_vector_type(4))) unsigned int u32x4;

#define SDIM 2048
#define DDIM 64
#define NBH  32

__device__ __forceinline__ unsigned short f2bf(float f) {
    union { float f; unsigned int u; } x;
    x.f = f;
    unsigned int u = x.u;
    u += 0x7FFFu + ((u >> 16) & 1u);  // round-to-nearest-even
    return (unsigned short)(u >> 16);
}

__device__ __forceinline__ unsigned int packbf(float a, float b) {
    return (unsigned int)f2bf(a) | ((unsigned int)f2bf(b) << 16);
}

// transpose [bh][R][C] f32 -> [bh][C][R] bf16(ushort), 64x64 tiles via LDS
__global__ __launch_bounds__(256) void transpose_cvt(
    const float* __restrict__ in, unsigned short* __restrict__ out,
    int R, int C)
{
    __shared__ float tile[64][65];
    const int bh = blockIdx.z;
    const int ct = blockIdx.x * 64;
    const int rt = blockIdx.y * 64;
    const float* src = in + (size_t)bh * R * C;
    unsigned short* dst = out + (size_t)bh * R * C;
    const int r = threadIdx.x >> 2;   // 0..63
    const int p = threadIdx.x & 3;    // 0..3
    const float* sp = src + (size_t)(rt + r) * C + ct + p * 16;
#pragma unroll
    for (int j = 0; j < 4; ++j) {
        f32x4 a = *(const f32x4*)(sp + j * 4);
        tile[r][p*16 + j*4 + 0] = a.x;
        tile[r][p*16 + j*4 + 1] = a.y;
        tile[r][p*16 + j*4 + 2] = a.z;
        tile[r][p*16 + j*4 + 3] = a.w;
    }
    __syncthreads();
    u32x4 w0, w1;
    w0.x = packbf(tile[p*16+ 0][r], tile[p*16+ 1][r]);
    w0.y = packbf(tile[p*16+ 2][r], tile[p*16+ 3][r]);
    w0.z = packbf(tile[p*16+ 4][r], tile[p*16+ 5][r]);
    w0.w = packbf(tile[p*16+ 6][r], tile[p*16+ 7][r]);
    w1.x = packbf(tile[p*16+ 8][r], tile[p*16+ 9][r]);
    w1.y = packbf(tile[p*16+10][r], tile[p*16+11][r]);
    w1.z = packbf(tile[p*16+12][r], tile[p*16+13][r]);
    w1.w = packbf(tile[p*16+14][r], tile[p*16+15][r]);
    unsigned short* dp = dst + (size_t)(ct + r) * R + rt + p * 16;
    *(u32x4*)dp = w0;
    *(u32x4*)(dp + 8) = w1;
}

// Fused attention, no-max softmax, ALL-FRAGMENT-LAYOUT pipeline.
// Since no-max softmax needs no cross-lane ops in the loop, the exp/prev/
// scores work happens directly on MFMA C/D fragments (col=ln, row=lg*4+r):
// prev loads + scores stores are scalar 4B nt ops (64B contiguous per
// quarter-wave; L2 merges to full lines). Only P crosses LDS (frag->A-frag
// transpose). K tile LDS-staged double-buffered as before. One barrier/iter.
__global__ __launch_bounds__(256, 4) void attn_fused(
    const float* __restrict__ q, const float* __restrict__ prev,
    const unsigned short* __restrict__ kT, const unsigned short* __restrict__ vT,
    float* __restrict__ out, float* __restrict__ scores)
{
    const int bh   = blockIdx.y;
    const int qt   = blockIdx.x;          // 64-row Q tile index
    const int tid  = threadIdx.x;
    const int wave = tid >> 6;
    const int lane = tid & 63;
    const int ln   = lane & 15;           // 0..15
    const int lg   = lane >> 4;           // 0..3

    __shared__ unsigned short ksmem[2][4096];   // K tile double buffer (swizzled)
    __shared__ unsigned short p_lds[64][72];    // P transpose buffer

    // ---- Q fragments (A operand: row = ln, k(d) = kc*32 + lg*8 + j) ----
    const int qrow_frag = qt * 64 + wave * 16 + ln;
    bf16x8 qf[2];
    {
        const float* qp = q + ((size_t)bh * SDIM + qrow_frag) * DDIM + lg * 8;
#pragma unroll
        for (int kc = 0; kc < 2; ++kc) {
            f32x4 a = *(const f32x4*)(qp + kc * 32);
            f32x4 b = *(const f32x4*)(qp + kc * 32 + 4);
            bf16x8 f;
            f[0] = (short)f2bf(a.x); f[1] = (short)f2bf(a.y);
            f[2] = (short)f2bf(a.z); f[3] = (short)f2bf(a.w);
            f[4] = (short)f2bf(b.x); f[5] = (short)f2bf(b.y);
            f[6] = (short)f2bf(b.z); f[7] = (short)f2bf(b.w);
            qf[kc] = f;
        }
    }

    const unsigned short* kbh   = kT + (size_t)bh * SDIM * DDIM;
    const unsigned short* vbase = vT + ((size_t)bh * DDIM + ln) * SDIM + lg * 8;

    // ---- fragment-layout prev/scores addressing ----
    // C/D element (nc, r): row = qt*64 + wave*16 + lg*4 + r, col = t0 + nc*16 + ln
    const int qrow_c = qt * 64 + wave * 16 + lg * 4;
    const float* prevF  = prev   + ((size_t)bh * SDIM + qrow_c) * SDIM + ln;
    float*       scoreF = scores + ((size_t)bh * SDIM + qrow_c) * SDIM + ln;

    // K staging identity: thread stages 16B chunks tid and tid+256 of 8KB tile
    const int c0 = tid ^ ((tid >> 3) & 7);            // swizzled dest chunk
    const int c1 = (tid + 256) ^ (((tid + 256) >> 3) & 7);

    f32x4 oacc[4] = {};
    f32x4 lacc = {0.0f, 0.0f, 0.0f, 0.0f};    // per-lane partial denominators

    // ---- prologue: stage K tile 0; prefetch prev tile 0 (fragment layout) ----
    {
        u32x4 kg0 = *(const u32x4*)(kbh + tid * 8);
        u32x4 kg1 = *(const u32x4*)(kbh + (tid + 256) * 8);
        *(u32x4*)&ksmem[0][c0 * 8] = kg0;
        *(u32x4*)&ksmem[0][c1 * 8] = kg1;
    }
    f32x4 pf[4];
#pragma unroll
    for (int nc = 0; nc < 4; ++nc)
#pragma unroll
        for (int r = 0; r < 4; ++r)
            pf[nc][r] = __builtin_nontemporal_load(prevF + (size_t)r * SDIM + nc * 16);
    __syncthreads();

    for (int tt = 0; tt < 32; ++tt) {
        const int t0  = tt * 64;
        const int buf = tt & 1;
        const bool more = tt < 31;

        // ---- A: issue next K tile's global loads (committed at end) ----
        u32x4 kg0, kg1;
        if (more) {
            const unsigned short* ktn = kbh + (size_t)(t0 + 64) * DDIM;
            kg0 = *(const u32x4*)(ktn + tid * 8);
            kg1 = *(const u32x4*)(ktn + (tid + 256) * 8);
        }

        // ---- B: S = Q @ K^T from LDS-staged K (swizzled reads) ----
        f32x4 sacc[4] = {};
        __builtin_amdgcn_s_setprio(1);
#pragma unroll
        for (int nc = 0; nc < 4; ++nc) {
            const int trow = nc * 16 + ln;
            const int sw = trow & 7;
#pragma unroll
            for (int kc = 0; kc < 2; ++kc) {
                bf16x8 bf = *(const bf16x8*)&ksmem[buf][trow * 64 + ((kc * 4 + lg) ^ sw) * 8];
                sacc[nc] = __builtin_amdgcn_mfma_f32_16x16x32_bf16(qf[kc], bf, sacc[nc], 0, 0, 0);
            }
        }
        __builtin_amdgcn_s_setprio(0);

        // ---- C: issue V loads (consumed at PV) ----
        bf16x8 vf[8];
#pragma unroll
        for (int nc = 0; nc < 4; ++nc)
#pragma unroll
            for (int kc = 0; kc < 2; ++kc)
                vf[nc * 2 + kc] = *(const bf16x8*)(vbase + (size_t)nc * 16 * SDIM + (t0 + kc * 32));

        // ---- D: fragment-layout epilogue of QK^T: scale+prev, scores, exp ----
        f32x4 p[4];
#pragma unroll
        for (int nc = 0; nc < 4; ++nc) {
#pragma unroll
            for (int r = 0; r < 4; ++r) {
                float s = sacc[nc][r] * 0.125f + pf[nc][r];
                __builtin_nontemporal_store(s, scoreF + (size_t)r * SDIM + t0 + nc * 16);
                p[nc][r] = __expf(s);
            }
        }
        lacc += p[0] + p[1] + p[2] + p[3];

        // ---- E: prefetch next tile's prev into pf (consumed next iter) ----
        if (more) {
#pragma unroll
            for (int nc = 0; nc < 4; ++nc)
#pragma unroll
                for (int r = 0; r < 4; ++r)
                    pf[nc][r] = __builtin_nontemporal_load(prevF + (size_t)r * SDIM + t0 + 64 + nc * 16);
        }

        // ---- F: P (bf16) -> LDS in row layout (frag -> A-frag transpose) ----
#pragma unroll
        for (int nc = 0; nc < 4; ++nc)
#pragma unroll
            for (int r = 0; r < 4; ++r)
                p_lds[wave * 16 + lg * 4 + r][nc * 16 + ln] = f2bf(p[nc][r]);

        // ---- G: O += P @ V ----
        bf16x8 pa[2];
#pragma unroll
        for (int kc = 0; kc < 2; ++kc)
            pa[kc] = *(const bf16x8*)&p_lds[wave * 16 + ln][kc * 32 + lg * 8];
        __builtin_amdgcn_s_setprio(1);
#pragma unroll
        for (int nc = 0; nc < 4; ++nc)
#pragma unroll
            for (int kc = 0; kc < 2; ++kc)
                oacc[nc] = __builtin_amdgcn_mfma_f32_16x16x32_bf16(pa[kc], vf[nc * 2 + kc], oacc[nc], 0, 0, 0);
        __builtin_amdgcn_s_setprio(0);

        // ---- H: commit next K tile to LDS; barrier ----
        if (more) {
            *(u32x4*)&ksmem[buf ^ 1][c0 * 8] = kg0;
            *(u32x4*)&ksmem[buf ^ 1][c1 * 8] = kg1;
        }
        __syncthreads();
    }

    // ---- epilogue: reduce l over the 16 col-lanes (scalar shuffles) ----
#pragma unroll
    for (int r = 0; r < 4; ++r) {
        float v = lacc[r];
        v += __shfl_xor(v, 1, 64);
        v += __shfl_xor(v, 2, 64);
        v += __shfl_xor(v, 4, 64);
        v += __shfl_xor(v, 8, 64);
        lacc[r] = v;
    }

    // ---- normalize + store O directly from fragment layout ----
    float* outF = out + ((size_t)bh * SDIM + qrow_c) * DDIM + ln;
#pragma unroll
    for (int r = 0; r < 4; ++r) {
        const float li = 1.0f / lacc[r];
#pragma unroll
        for (int nc = 0; nc < 4; ++nc)
            outF[(size_t)r * DDIM + nc * 16] = oacc[nc][r] * li;
    }
}

extern "C" void kernel_launch(void* const* d_in, const int* in_sizes, int n_in,
                              void* d_out, int out_size, void* d_ws, size_t ws_size,
                              hipStream_t stream) {
    const float* q    = (const float*)d_in[0];
    const float* k    = (const float*)d_in[1];
    const float* v    = (const float*)d_in[2];
    const float* prev = (const float*)d_in[3];

    float* out    = (float*)d_out;
    float* scores = out + (size_t)NBH * SDIM * DDIM;   // outputs concatenated

    unsigned short* kT = (unsigned short*)d_ws;                 // [bh][2048][64] bf16
    unsigned short* vT = kT + (size_t)NBH * SDIM * DDIM;        // [bh][64][2048] bf16

    // k: [bh][64][2048] -> kT [bh][2048][64]
    transpose_cvt<<<dim3(SDIM / 64, 1, NBH), 256, 0, stream>>>(k, kT, DDIM, SDIM);
    // v: [bh][2048][64] -> vT [bh][64][2048]
    transpose_cvt<<<dim3(1, SDIM / 64, NBH), 256, 0, stream>>>(v, vT, SDIM, DDIM);

    attn_fused<<<dim3(SDIM / 64, NBH), 256, 0, stream>>>(q, prev, kT, vT, out, scores);
}